// Round 7
// baseline (1037.932 us; speedup 1.0000x reference)
//
#include <hip/hip_runtime.h>

typedef long long i64;

// ---------------------------------------------------------------------------
// S1=S2=256, B=8, C0=32.  d_out = 22,151,168 float32 = REAL parts of:
//   out0 (8,32,256,129) | out1 (alias of out0) | out2 (8,64,128,64) | out3 (8,64,64,32)
// No workspace used — the network is pointwise in mapped space, so the
// down/up paths are fused per-point (corner maps are identity-on-subsets).
// NOTE: "+1" skips add (1+0j): REAL PART ONLY (this was the R1-R6 bug).
// ---------------------------------------------------------------------------
#define BB   8
#define SS1  256
#define MM2  129
#define SP0  (SS1*MM2)    // 33024

#define O0 0LL
#define O1 8454144LL
#define O2 16908288LL
#define O3 21102592LL
// total floats = 22151168

__device__ __forceinline__ float ldf(const float* p, i64 i, i64 cap) {
    return (i >= 0 && i < cap) ? p[i] : 0.0f;
}
__device__ __forceinline__ void stf(float* p, i64 i, i64 cap, float v) {
    if (i >= 0 && i < cap) p[i] = v;
}

__device__ __forceinline__ float tanh_fast(float x) {
    float a = fabsf(x);
    float t = __expf(-2.0f * a);
    float r = (1.0f - t) / (1.0f + t);
    return copysignf(r, x);
}
__device__ __forceinline__ float gelu_f(float x) {
    // jax.nn.gelu(approximate=True)
    float inner = 0.7978845608028654f * (x + 0.044715f * x * x * x);
    return 0.5f * x * (1.0f + tanh_fast(inner));
}

// ---------------------------------------------------------------------------
// Shared: compute v[c] = mask(x*re_feature) + skip(1) for all 32 channels
// at spatial point (b, x, y).  vr gets the +1 (real skip), vi does not.
// ---------------------------------------------------------------------------
__device__ __forceinline__ void l0_masked_v(
    int b, int x, int y,
    const float* __restrict__ xr, const float* __restrict__ xi,
    const float* __restrict__ Re,
    const float2* s_w1, const float2* s_b1,
    const float2* s_w2, const float2* s_b2,
    float* vr, float* vi)
{
    // k features: channel c = f*2+d, value k_d^((f+1)/3), principal branch
    float kv0 = (x < 128) ? (float)x : (float)(x - 256);
    float kv1 = (y < 128) ? (float)y : -128.0f;   // y==128 -> -128
    const float P[3] = {1.0f/3.0f, 2.0f/3.0f, 1.0f};
    float fr[6], fi[6];
    #pragma unroll
    for (int d = 0; d < 2; d++) {
        float k = (d == 0) ? kv0 : kv1;
        float lg = __logf(fabsf(k));
        #pragma unroll
        for (int f = 0; f < 3; f++) {
            int c = f * 2 + d;
            float m = __expf(P[f] * lg);
            if (k == 0.0f)      { fr[c] = 0.0f; fi[c] = 0.0f; }
            else if (k > 0.0f)  { fr[c] = m;    fi[c] = 0.0f; }
            else {
                float ang = P[f] * 3.14159274101257f;
                fr[c] = m * __cosf(ang);
                fi[c] = m * __sinf(ang);
            }
        }
    }
    float lre = __logf(Re[b]);
    float rp[3];
    #pragma unroll
    for (int f = 0; f < 3; f++) rp[f] = __expf(P[f] * lre);

    // layer 1 (9 -> 32) + cgelu
    float hr[32], hi[32];
    #pragma unroll
    for (int o = 0; o < 32; o++) {
        float ar = s_b1[o].x, ai = s_b1[o].y;
        #pragma unroll
        for (int i = 0; i < 6; i++) {
            float2 w = s_w1[o * 9 + i];
            ar += w.x * fr[i] - w.y * fi[i];
            ai += w.x * fi[i] + w.y * fr[i];
        }
        #pragma unroll
        for (int i = 0; i < 3; i++) {
            float2 w = s_w1[o * 9 + 6 + i];
            ar += w.x * rp[i];
            ai += w.y * rp[i];
        }
        hr[o] = gelu_f(ar);
        hi[o] = gelu_f(ai);
    }

    // layer 2 (32 -> 32) = re_feature; x*rf; mask; +1 (real only)
    i64 base0 = (i64)b * 32 * SP0 + (i64)x * MM2 + y;
    for (int c = 0; c < 32; c++) {
        float rr = s_b2[c].x, ri = s_b2[c].y;
        #pragma unroll
        for (int i = 0; i < 32; i++) {
            float2 w = s_w2[c * 32 + i];
            rr += w.x * hr[i] - w.y * hi[i];
            ri += w.x * hi[i] + w.y * hr[i];
        }
        float xre = xr[base0 + (i64)c * SP0];
        float xim = xi[base0 + (i64)c * SP0];
        float pr = xre * rr - xim * ri;
        float pi = xre * ri + xim * rr;
        if (sqrtf(pr * pr + pi * pi) <= 0.05f) { pr = 0.0f; pi = 0.0f; }
        vr[c] = pr + 1.0f;
        vi[c] = pi;
    }
}

#define STAGE_L0()                                                            \
    for (int t = threadIdx.x; t < 1024; t += 256) {                           \
        s_w2[t] = make_float2(w2r[t], w2i[t]);                                \
        s_w0[t] = make_float2(w0r[t], w0i[t]);                                \
        if (t < 288) s_w1[t] = make_float2(w1r[t], w1i[t]);                   \
        if (t < 32) {                                                         \
            s_b1[t] = make_float2(b1r[t], b1i[t]);                            \
            s_b2[t] = make_float2(b2r[t], b2i[t]);                            \
        }                                                                     \
    }

// ---------------------------------------------------------------------------
// K1: all points — real(x1_0) = gelu(real(W0-mix)) -> out0, out1
// ---------------------------------------------------------------------------
__global__ __launch_bounds__(256) void k_level0(
    const float* __restrict__ xr, const float* __restrict__ xi,
    const float* __restrict__ Re,
    const float* __restrict__ w1r, const float* __restrict__ w1i,
    const float* __restrict__ b1r, const float* __restrict__ b1i,
    const float* __restrict__ w2r, const float* __restrict__ w2i,
    const float* __restrict__ b2r, const float* __restrict__ b2i,
    const float* __restrict__ w0r, const float* __restrict__ w0i,
    float* __restrict__ of, i64 capf)
{
    __shared__ float2 s_w1[288], s_b1[32], s_w2[1024], s_b2[32], s_w0[1024];
    STAGE_L0();
    __syncthreads();

    int idx = blockIdx.x * 256 + threadIdx.x;
    if (idx >= BB * SP0) return;
    int y  = idx % MM2;
    int t2 = idx / MM2;
    int x  = t2 % SS1;
    int b  = t2 / SS1;

    float vr[32], vi[32];
    l0_masked_v(b, x, y, xr, xi, Re, s_w1, s_b1, s_w2, s_b2, vr, vi);

    i64 base0 = (i64)b * 32 * SP0 + (i64)x * MM2 + y;
    #pragma unroll
    for (int o = 0; o < 32; o++) {
        float a = 0.0f;
        #pragma unroll
        for (int c = 0; c < 32; c++) {
            float2 w = s_w0[c * 32 + o];   // w0[i][o] ('io' einsum)
            a += w.x * vr[c] - w.y * vi[c];
        }
        float g = gelu_f(a);
        i64 oi = base0 + (i64)o * SP0;
        stf(of, O0 + oi, capf, g);
        stf(of, O1 + oi, capf, g);
    }
}

// ---------------------------------------------------------------------------
// K2: corner1 \ corner2 points (level-1 grid r1 in [0,128), y in [0,64)).
// Recompute level-0 complex, v1 = cgelu(Wd1)+(1+0j) -> out2; u1 real -> out0/out1.
// ---------------------------------------------------------------------------
__global__ __launch_bounds__(256) void k_branch1(
    const float* __restrict__ xr, const float* __restrict__ xi,
    const float* __restrict__ Re,
    const float* __restrict__ w1r, const float* __restrict__ w1i,
    const float* __restrict__ b1r, const float* __restrict__ b1i,
    const float* __restrict__ w2r, const float* __restrict__ w2i,
    const float* __restrict__ b2r, const float* __restrict__ b2i,
    const float* __restrict__ w0r, const float* __restrict__ w0i,
    const float* __restrict__ wd1r, const float* __restrict__ wd1i,
    const float* __restrict__ wu1r, const float* __restrict__ wu1i,
    float* __restrict__ of, i64 capf)
{
    __shared__ float2 s_w1[288], s_b1[32], s_w2[1024], s_b2[32], s_w0[1024];
    __shared__ float2 s_wd1[2048];   // [o][i] = wd1[i][o]
    __shared__ float2 s_wu1[2048];   // [c][o] natural
    STAGE_L0();
    for (int t = threadIdx.x; t < 2048; t += 256) {
        int o = t >> 5, i = t & 31;
        s_wd1[t] = make_float2(wd1r[i * 64 + o], wd1i[i * 64 + o]);
        s_wu1[t] = make_float2(wu1r[t], wu1i[t]);
    }
    __syncthreads();

    int idx = blockIdx.x * 256 + threadIdx.x;   // 65536
    if (idx >= 65536) return;
    int y  = idx & 63;
    int r1 = (idx >> 6) & 127;
    int b  = idx >> 13;
    if ((y < 32) && (r1 < 32 || r1 >= 96)) return;   // corner2 -> K3
    int x0 = (r1 < 64) ? r1 : r1 + 128;

    float vr[32], vi[32];
    l0_masked_v(b, x0, y, xr, xi, Re, s_w1, s_b1, s_w2, s_b2, vr, vi);

    // full complex W0 mix -> x1 (level-0 map, complex)
    float x1r[32], x1i[32];
    #pragma unroll
    for (int o = 0; o < 32; o++) {
        float ar = 0.0f, ai = 0.0f;
        #pragma unroll
        for (int c = 0; c < 32; c++) {
            float2 w = s_w0[c * 32 + o];
            ar += w.x * vr[c] - w.y * vi[c];
            ai += w.x * vi[c] + w.y * vr[c];
        }
        x1r[o] = gelu_f(ar);
        x1i[o] = gelu_f(ai);
    }

    // down1: v1 = cgelu(Wd1 mix) + (1+0j) ; real -> out2
    float v1r[64], v1i[64];
    for (int o = 0; o < 64; o++) {
        float ar = 0.0f, ai = 0.0f;
        #pragma unroll
        for (int i = 0; i < 32; i++) {
            float2 w = s_wd1[o * 32 + i];
            ar += w.x * x1r[i] - w.y * x1i[i];
            ai += w.x * x1i[i] + w.y * x1r[i];
        }
        v1r[o] = gelu_f(ar) + 1.0f;
        v1i[o] = gelu_f(ai);          // +1 is REAL ONLY
        stf(of, O2 + ((i64)(b * 64 + o) * 128 + r1) * 64 + y, capf, v1r[o]);
    }

    // up1: real(u1) added into out0/out1
    i64 base0 = (i64)b * 32 * SP0 + (i64)x0 * MM2 + y;
    #pragma unroll
    for (int o = 0; o < 32; o++) {
        float rs = 0.0f;
        for (int c = 0; c < 64; c++) {
            float2 w = s_wu1[c * 32 + o];
            rs += w.x * v1r[c] - w.y * v1i[c];
        }
        float u = gelu_f(rs);
        i64 oi = base0 + (i64)o * SP0;
        stf(of, O0 + oi, capf, ldf(of, O0 + oi, capf) + u);
        stf(of, O1 + oi, capf, ldf(of, O1 + oi, capf) + u);
    }
}

// ---------------------------------------------------------------------------
// K3: corner2 points (level-2 grid r2 in [0,64), y in [0,32)).
// level-0 -> Wd1 -> v1 ; Wd2 -> v2 -> out3 ; Wu2 -> v1 += u2 -> out2 ;
// Wu1 real -> add out0/out1.  Wd2/Wu2 read from global (uniform indices).
// ---------------------------------------------------------------------------
__global__ __launch_bounds__(256) void k_branch2(
    const float* __restrict__ xr, const float* __restrict__ xi,
    const float* __restrict__ Re,
    const float* __restrict__ w1r, const float* __restrict__ w1i,
    const float* __restrict__ b1r, const float* __restrict__ b1i,
    const float* __restrict__ w2r, const float* __restrict__ w2i,
    const float* __restrict__ b2r, const float* __restrict__ b2i,
    const float* __restrict__ w0r, const float* __restrict__ w0i,
    const float* __restrict__ wd1r, const float* __restrict__ wd1i,
    const float* __restrict__ wu1r, const float* __restrict__ wu1i,
    const float* __restrict__ wd2r, const float* __restrict__ wd2i,
    const float* __restrict__ wu2r, const float* __restrict__ wu2i,
    float* __restrict__ of, i64 capf)
{
    __shared__ float2 s_w1[288], s_b1[32], s_w2[1024], s_b2[32], s_w0[1024];
    __shared__ float2 s_wd1[2048];
    __shared__ float2 s_wu1[2048];
    STAGE_L0();
    for (int t = threadIdx.x; t < 2048; t += 256) {
        int o = t >> 5, i = t & 31;
        s_wd1[t] = make_float2(wd1r[i * 64 + o], wd1i[i * 64 + o]);
        s_wu1[t] = make_float2(wu1r[t], wu1i[t]);
    }
    __syncthreads();

    int idx = blockIdx.x * 256 + threadIdx.x;   // 16384
    if (idx >= 16384) return;
    int y  = idx & 31;
    int r2 = (idx >> 5) & 63;
    int b  = idx >> 11;
    int r1 = (r2 < 32) ? r2 : r2 + 64;          // level-1 row
    int x0 = (r1 < 64) ? r1 : r1 + 128;         // level-0 row

    float vr[32], vi[32];
    l0_masked_v(b, x0, y, xr, xi, Re, s_w1, s_b1, s_w2, s_b2, vr, vi);

    float x1r[32], x1i[32];
    #pragma unroll
    for (int o = 0; o < 32; o++) {
        float ar = 0.0f, ai = 0.0f;
        #pragma unroll
        for (int c = 0; c < 32; c++) {
            float2 w = s_w0[c * 32 + o];
            ar += w.x * vr[c] - w.y * vi[c];
            ai += w.x * vi[c] + w.y * vr[c];
        }
        x1r[o] = gelu_f(ar);
        x1i[o] = gelu_f(ai);
    }

    // down1 -> v1 (no store yet; this point's out2 gets the u2 add below)
    float v1r[64], v1i[64];
    for (int o = 0; o < 64; o++) {
        float ar = 0.0f, ai = 0.0f;
        #pragma unroll
        for (int i = 0; i < 32; i++) {
            float2 w = s_wd1[o * 32 + i];
            ar += w.x * x1r[i] - w.y * x1i[i];
            ai += w.x * x1i[i] + w.y * x1r[i];
        }
        v1r[o] = gelu_f(ar) + 1.0f;
        v1i[o] = gelu_f(ai);          // +1 is REAL ONLY
    }

    // down2 -> v2 ; real -> out3
    float v2r[64], v2i[64];
    for (int o = 0; o < 64; o++) {
        float ar = 0.0f, ai = 0.0f;
        for (int c = 0; c < 64; c++) {
            float wr = wd2r[c * 64 + o], wi_ = wd2i[c * 64 + o];
            ar += wr * v1r[c] - wi_ * v1i[c];
            ai += wr * v1i[c] + wi_ * v1r[c];
        }
        v2r[o] = gelu_f(ar) + 1.0f;
        v2i[o] = gelu_f(ai);          // +1 is REAL ONLY
        stf(of, O3 + ((i64)(b * 64 + o) * 64 + r2) * 32 + y, capf, v2r[o]);
    }

    // up2: v1 += cgelu(Wu2 mix of v2) ; real(v1) -> out2
    for (int o = 0; o < 64; o++) {
        float ar = 0.0f, ai = 0.0f;
        for (int c = 0; c < 64; c++) {
            float wr = wu2r[c * 64 + o], wi_ = wu2i[c * 64 + o];
            ar += wr * v2r[c] - wi_ * v2i[c];
            ai += wr * v2i[c] + wi_ * v2r[c];
        }
        v1r[o] += gelu_f(ar);
        v1i[o] += gelu_f(ai);
        stf(of, O2 + ((i64)(b * 64 + o) * 128 + r1) * 64 + y, capf, v1r[o]);
    }

    // up1: real(u1) into out0/out1
    i64 base0 = (i64)b * 32 * SP0 + (i64)x0 * MM2 + y;
    #pragma unroll
    for (int o = 0; o < 32; o++) {
        float rs = 0.0f;
        for (int c = 0; c < 64; c++) {
            float2 w = s_wu1[c * 32 + o];
            rs += w.x * v1r[c] - w.y * v1i[c];
        }
        float u = gelu_f(rs);
        i64 oi = base0 + (i64)o * SP0;
        stf(of, O0 + oi, capf, ldf(of, O0 + oi, capf) + u);
        stf(of, O1 + oi, capf, ldf(of, O1 + oi, capf) + u);
    }
}

// ---------------------------------------------------------------------------
extern "C" void kernel_launch(void* const* d_in, const int* in_sizes, int n_in,
                              void* d_out, int out_size, void* d_ws, size_t ws_size,
                              hipStream_t stream) {
    const float* xr   = (const float*)d_in[0];
    const float* xi   = (const float*)d_in[1];
    const float* Re   = (const float*)d_in[2];
    const float* w1r  = (const float*)d_in[3];
    const float* w1i  = (const float*)d_in[4];
    const float* b1r  = (const float*)d_in[5];
    const float* b1i  = (const float*)d_in[6];
    const float* w2r  = (const float*)d_in[7];
    const float* w2i  = (const float*)d_in[8];
    const float* b2r  = (const float*)d_in[9];
    const float* b2i  = (const float*)d_in[10];
    const float* w0r  = (const float*)d_in[11];
    const float* w0i  = (const float*)d_in[12];
    const float* wd1r = (const float*)d_in[13];
    const float* wd1i = (const float*)d_in[14];
    const float* wu1r = (const float*)d_in[15];
    const float* wu1i = (const float*)d_in[16];
    const float* wd2r = (const float*)d_in[17];
    const float* wd2i = (const float*)d_in[18];
    const float* wu2r = (const float*)d_in[19];
    const float* wu2i = (const float*)d_in[20];

    float* of  = (float*)d_out;
    i64 capf   = (i64)out_size;   // floats

    k_level0<<<dim3((BB * SP0 + 255) / 256), 256, 0, stream>>>(
        xr, xi, Re, w1r, w1i, b1r, b1i, w2r, w2i, b2r, b2i, w0r, w0i, of, capf);
    k_branch1<<<dim3(256), 256, 0, stream>>>(
        xr, xi, Re, w1r, w1i, b1r, b1i, w2r, w2i, b2r, b2i, w0r, w0i,
        wd1r, wd1i, wu1r, wu1i, of, capf);
    k_branch2<<<dim3(64), 256, 0, stream>>>(
        xr, xi, Re, w1r, w1i, b1r, b1i, w2r, w2i, b2r, b2i, w0r, w0i,
        wd1r, wd1i, wu1r, wu1i, wd2r, wd2i, wu2r, wu2i, of, capf);
}